// Round 1
// baseline (957.540 us; speedup 1.0000x reference)
//
#include <hip/hip_runtime.h>

// VMamba mixer forward, MI355X. fp32 throughout.
// B=8, H=W=56 (L=3136), D_MODEL=96, D_INNER=192, DT_RANK=6, HEAD_D=32,
// D_STATE=32, K=4 scan directions. Chunked parallel selective scan.

constexpr int DM   = 96;     // D_MODEL
constexpr int DI   = 192;    // D_INNER
constexpr int RK   = 6;      // DT_RANK
constexpr int NS   = 32;     // D_STATE (== HEAD_D)
constexpr int KD   = 4;      // directions
constexpr int HW   = 56;
constexpr int LT   = 3136;   // L = 56*56
constexpr int NB   = 8;      // batch
constexpr int NPOS = NB * LT;   // 25088
constexpr int NC   = 16;     // chunks per sequence
constexpr int CH   = 196;    // chunk length (16*196 = 3136)

__device__ __forceinline__ float siluf(float x) { return x / (1.f + __expf(-x)); }

// sequence index l of direction k  ->  spatial position p (row-major h*56+w)
__device__ __forceinline__ int seq2pos(int k, int l) {
  int m = (k & 2) ? (LT - 1 - l) : l;
  return (k & 1) ? ((m % HW) * HW + m / HW) : m;
}

// ---------------- Kernel 1: in_proj + split + silu(z) ----------------
// x (NPOS,96) @ Wi^T (384,96) -> xi (NPOS,192), zs = silu(rest)
__global__ __launch_bounds__(384) void k_inproj(const float* __restrict__ x,
                                                const float* __restrict__ Wi,
                                                float* __restrict__ xi,
                                                float* __restrict__ zs) {
  const int PPB = 16;
  __shared__ float sx[PPB][DM];
  int p0 = blockIdx.x * PPB;
  int tid = threadIdx.x;
  for (int i = tid; i < PPB * DM; i += 384) sx[i / DM][i % DM] = x[p0 * DM + i];
  __syncthreads();
  int o = tid;  // output column 0..383
  float acc[PPB];
#pragma unroll
  for (int p = 0; p < PPB; p++) acc[p] = 0.f;
  const float* wr = Wi + o * DM;
  for (int kk = 0; kk < DM; kk++) {
    float w = wr[kk];
#pragma unroll
    for (int p = 0; p < PPB; p++) acc[p] += w * sx[p][kk];
  }
  if (o < DI) {
    for (int p = 0; p < PPB; p++) xi[(p0 + p) * DI + o] = acc[p];
  } else {
    int oz = o - DI;
    for (int p = 0; p < PPB; p++) zs[(p0 + p) * DI + oz] = siluf(acc[p]);
  }
}

// ---------------- Kernel 2: depthwise 3x3 conv + bias + silu ----------------
__global__ void k_conv(const float* __restrict__ xi, const float* __restrict__ cw,
                       const float* __restrict__ cb, float* __restrict__ xc) {
  int t = blockIdx.x * 256 + threadIdx.x;
  if (t >= NPOS * DI) return;
  int c = t % DI;
  int pos = t / DI;
  int p = pos % LT, b = pos / LT;
  int h = p / HW, w = p % HW;
  float acc = cb[c];
#pragma unroll
  for (int dh = 0; dh < 3; dh++) {
    int hh = h + dh - 1;
    if (hh < 0 || hh >= HW) continue;
#pragma unroll
    for (int dw = 0; dw < 3; dw++) {
      int ww = w + dw - 1;
      if (ww < 0 || ww >= HW) continue;
      acc += cw[(dh * 3 + dw) * DI + c] * xi[(b * LT + hh * HW + ww) * DI + c];
    }
  }
  xc[t] = siluf(acc);
}

// ---------------- Kernel 3: x_proj (4 dirs) + softplus/exp ----------------
// per spatial position: out[k][c] = dot(xc[pos], Wp[k][c][:]) , c in [0,70)
__global__ __launch_bounds__(320) void k_xproj(const float* __restrict__ xc,
                                               const float* __restrict__ Wp,
                                               const float* __restrict__ A_logs,
                                               const float* __restrict__ dt_bias,
                                               float* __restrict__ dtb,
                                               float* __restrict__ dAb,
                                               float* __restrict__ Bsb,
                                               float* __restrict__ Csb) {
  const int PPB = 8;
  __shared__ float sx[PPB][DI];
  int p0 = blockIdx.x * PPB;
  int tid = threadIdx.x;
  for (int i = tid; i < PPB * DI; i += 320) sx[i / DI][i % DI] = xc[p0 * DI + i];
  __syncthreads();
  if (tid >= 280) return;
  int k = tid / 70, c = tid % 70;
  float acc[PPB];
#pragma unroll
  for (int p = 0; p < PPB; p++) acc[p] = 0.f;
  const float* wr = Wp + tid * DI;  // Wp is [K][70][192] contiguous
  for (int j = 0; j < DI; j++) {
    float w = wr[j];
#pragma unroll
    for (int p = 0; p < PPB; p++) acc[p] += w * sx[p][j];
  }
  if (c < RK) {
    float bias = dt_bias[k * RK + c];
    float Av = -__expf(A_logs[k * RK + c]);
    for (int p = 0; p < PPB; p++) {
      float v = acc[p] + bias;
      float dtv = (v > 20.f) ? v : log1pf(__expf(v));
      int idx = ((p0 + p) * KD + k) * RK + c;
      dtb[idx] = dtv;
      dAb[idx] = __expf(dtv * Av);
    }
  } else if (c < RK + NS) {
    for (int p = 0; p < PPB; p++) Bsb[((p0 + p) * KD + k) * NS + (c - RK)] = acc[p];
  } else {
    for (int p = 0; p < PPB; p++) Csb[((p0 + p) * KD + k) * NS + (c - RK - NS)] = acc[p];
  }
}

// ---------------- Kernel 4: chunked local scan ----------------
// block = 192 threads, thread = (r,d). 512 blocks = (b,k,chunk).
__global__ __launch_bounds__(192) void k_scanA(const float* __restrict__ xc,
                                               const float* __restrict__ dtb,
                                               const float* __restrict__ dAb,
                                               const float* __restrict__ Bsb,
                                               const float* __restrict__ Csb,
                                               const float* __restrict__ Ds,
                                               float* __restrict__ ybuf,
                                               float* __restrict__ cumdA,
                                               float* __restrict__ Send,
                                               float* __restrict__ Pend) {
  int bi = blockIdx.x;
  int chunk = bi % NC;
  int k = (bi / NC) & 3;
  int b = bi / (NC * KD);
  int tid = threadIdx.x;
  int r = tid >> 5, d = tid & 31;
  __shared__ float sB[2][NS], sC[2][NS], sdA[2][8], sdt[2][8];
  float S[NS];
#pragma unroll
  for (int n = 0; n < NS; n++) S[n] = 0.f;
  float cum = 1.f;
  float Dsv = Ds[(k * RK + r) * NS + d];
  int l0 = chunk * CH;
  {  // prefetch step 0
    int p = seq2pos(k, l0);
    int base = (b * LT + p) * KD + k;
    if (tid < 32) sB[0][tid] = Bsb[base * NS + tid];
    else if (tid < 64) sC[0][tid - 32] = Csb[base * NS + tid - 32];
    else if (tid < 70) sdA[0][tid - 64] = dAb[base * RK + tid - 64];
    else if (tid < 76) sdt[0][tid - 70] = dtb[base * RK + tid - 70];
  }
  for (int l = 0; l < CH; l++) {
    __syncthreads();
    int cur = l & 1;
    if (l + 1 < CH) {  // prefetch next step into other buffer
      int p1 = seq2pos(k, l0 + l + 1);
      int base = (b * LT + p1) * KD + k;
      int nb = cur ^ 1;
      if (tid < 32) sB[nb][tid] = Bsb[base * NS + tid];
      else if (tid < 64) sC[nb][tid - 32] = Csb[base * NS + tid - 32];
      else if (tid < 70) sdA[nb][tid - 64] = dAb[base * RK + tid - 64];
      else if (tid < 76) sdt[nb][tid - 70] = dtb[base * RK + tid - 70];
    }
    int p = seq2pos(k, l0 + l);
    int gbase = b * LT + p;
    float xv = xc[gbase * DI + tid];  // tid == r*32+d == d_inner index
    float dAr = sdA[cur][r], dtr = sdt[cur][r];
    float xdt = xv * dtr;
    float y = 0.f;
#pragma unroll
    for (int n = 0; n < NS; n++) {
      S[n] = S[n] * dAr + xdt * sB[cur][n];
      y += S[n] * sC[cur][n];
    }
    cum *= dAr;
    ybuf[((b * KD + k) * LT + p) * DI + tid] = y + xv * Dsv;
    if (d == 0) cumdA[(gbase * KD + k) * RK + r] = cum;
  }
  int sb = ((b * KD + k) * NC + chunk) * (RK * NS * NS);
#pragma unroll
  for (int n = 0; n < NS; n++) Send[sb + tid * NS + n] = S[n];
  if (d == 0) Pend[((b * KD + k) * NC + chunk) * RK + r] = cum;
}

// ---------------- Kernel 5: sequential chunk-state combine ----------------
__global__ __launch_bounds__(256) void k_scanB(const float* __restrict__ Send,
                                               const float* __restrict__ Pend,
                                               float* __restrict__ Sinit) {
  int bk = blockIdx.x;  // 32 sequences
  int tid = threadIdx.x;
  const int EL = RK * NS * NS / 256;  // 24
  float run[EL];
#pragma unroll
  for (int j = 0; j < EL; j++) run[j] = 0.f;
  for (int c = 0; c < NC; c++) {
    int sb = (bk * NC + c) * (RK * NS * NS);
#pragma unroll
    for (int j = 0; j < EL; j++) {
      int e = tid + j * 256;
      Sinit[sb + e] = run[j];
      float pe = Pend[(bk * NC + c) * RK + (e >> 10)];  // r = e/1024
      run[j] = run[j] * pe + Send[sb + e];
    }
  }
}

// ---------------- Kernel 6: fixup  y += cumdA * (S_init . C) ----------------
__global__ __launch_bounds__(192) void k_scanC(const float* __restrict__ Csb,
                                               const float* __restrict__ cumdA,
                                               const float* __restrict__ Sinit,
                                               float* __restrict__ ybuf) {
  int bi = blockIdx.x;
  int chunk = bi % NC;
  if (chunk == 0) return;  // S_init == 0
  int k = (bi / NC) & 3;
  int b = bi / (NC * KD);
  int tid = threadIdx.x;
  int r = tid >> 5;
  float S[NS];
  int sb = ((b * KD + k) * NC + chunk) * (RK * NS * NS);
#pragma unroll
  for (int n = 0; n < NS; n++) S[n] = Sinit[sb + tid * NS + n];
  __shared__ float sC[2][NS], scum[2][8];
  int l0 = chunk * CH;
  {
    int p = seq2pos(k, l0);
    int base = (b * LT + p) * KD + k;
    if (tid < 32) sC[0][tid] = Csb[base * NS + tid];
    else if (tid < 38) scum[0][tid - 32] = cumdA[base * RK + tid - 32];
  }
  for (int l = 0; l < CH; l++) {
    __syncthreads();
    int cur = l & 1;
    if (l + 1 < CH) {
      int p1 = seq2pos(k, l0 + l + 1);
      int base = (b * LT + p1) * KD + k;
      int nb = cur ^ 1;
      if (tid < 32) sC[nb][tid] = Csb[base * NS + tid];
      else if (tid < 38) scum[nb][tid - 32] = cumdA[base * RK + tid - 32];
    }
    float y = 0.f;
#pragma unroll
    for (int n = 0; n < NS; n++) y += S[n] * sC[cur][n];
    int p = seq2pos(k, l0 + l);
    ybuf[((b * KD + k) * LT + p) * DI + tid] += y * scum[cur][r];
  }
}

// ---------------- Kernel 7: merge + LN + gelu + *silu(z) + out_proj ----------------
__global__ __launch_bounds__(192) void k_out(const float* __restrict__ ybuf,
                                             const float* __restrict__ zs,
                                             const float* __restrict__ ln_g,
                                             const float* __restrict__ ln_b,
                                             const float* __restrict__ Wo,
                                             float* __restrict__ out) {
  int pos = blockIdx.x;  // b*LT + p
  int b = pos / LT, p = pos % LT;
  int tid = threadIdx.x;  // 0..191
  float v = 0.f;
#pragma unroll
  for (int k = 0; k < KD; k++) v += ybuf[((b * KD + k) * LT + p) * DI + tid];
  float s1 = v, s2 = v * v;
#pragma unroll
  for (int off = 32; off; off >>= 1) {
    s1 += __shfl_down(s1, off, 64);
    s2 += __shfl_down(s2, off, 64);
  }
  __shared__ float rs1[3], rs2[3];
  int wave = tid >> 6, lane = tid & 63;
  if (lane == 0) { rs1[wave] = s1; rs2[wave] = s2; }
  __syncthreads();
  float mean = (rs1[0] + rs1[1] + rs1[2]) * (1.f / 192.f);
  float var = (rs2[0] + rs2[1] + rs2[2]) * (1.f / 192.f) - mean * mean;
  float rstd = rsqrtf(var + 1e-5f);
  float t = (v - mean) * rstd * ln_g[tid] + ln_b[tid];
  float ge = 0.5f * t * (1.f + erff(t * 0.70710678118f));
  float u = ge * zs[pos * DI + tid];
  __shared__ float su[DI];
  su[tid] = u;
  __syncthreads();
  int o = tid % DM, half = tid / DM;  // 2 threads per output
  const float* wr = Wo + o * DI + half * DM;
  const float* uu = su + half * DM;
  float acc = 0.f;
#pragma unroll
  for (int j = 0; j < DM; j++) acc += wr[j] * uu[j];
  __shared__ float part[DI];
  part[tid] = acc;
  __syncthreads();
  if (tid < DM) out[pos * DM + tid] = part[tid] + part[tid + DM];
}

extern "C" void kernel_launch(void* const* d_in, const int* in_sizes, int n_in,
                              void* d_out, int out_size, void* d_ws, size_t ws_size,
                              hipStream_t stream) {
  const float* x       = (const float*)d_in[0];
  const float* Wi      = (const float*)d_in[1];
  const float* cw      = (const float*)d_in[2];
  const float* cb      = (const float*)d_in[3];
  const float* Wp      = (const float*)d_in[4];
  const float* Ds      = (const float*)d_in[5];
  const float* A_logs  = (const float*)d_in[6];
  const float* dt_bias = (const float*)d_in[7];
  const float* ln_g    = (const float*)d_in[8];
  const float* ln_b    = (const float*)d_in[9];
  const float* Wo      = (const float*)d_in[10];
  float* out = (float*)d_out;

  float* ws = (float*)d_ws;
  float* xi    = ws;                       // NPOS*DI      = 4,816,896
  float* zs    = xi + (size_t)NPOS * DI;
  float* xc    = zs + (size_t)NPOS * DI;
  float* dtb   = xc + (size_t)NPOS * DI;   // NPOS*KD*RK   = 602,112
  float* dAb   = dtb + (size_t)NPOS * KD * RK;
  float* Bsb   = dAb + (size_t)NPOS * KD * RK;   // NPOS*KD*NS = 3,211,264
  float* Csb   = Bsb + (size_t)NPOS * KD * NS;
  float* cum   = Csb + (size_t)NPOS * KD * NS;   // NPOS*KD*RK
  float* ybuf  = cum + (size_t)NPOS * KD * RK;   // NB*KD*LT*DI = 19,267,584
  float* Send  = ybuf + (size_t)NB * KD * LT * DI;  // 32*16*6144
  float* Sinit = Send + (size_t)32 * NC * RK * NS * NS;
  float* Pend  = Sinit + (size_t)32 * NC * RK * NS * NS;  // 32*16*6

  k_inproj<<<NPOS / 16, 384, 0, stream>>>(x, Wi, xi, zs);
  k_conv<<<(NPOS * DI + 255) / 256, 256, 0, stream>>>(xi, cw, cb, xc);
  k_xproj<<<NPOS / 8, 320, 0, stream>>>(xc, Wp, A_logs, dt_bias, dtb, dAb, Bsb, Csb);
  k_scanA<<<NB * KD * NC, 192, 0, stream>>>(xc, dtb, dAb, Bsb, Csb, Ds, ybuf, cum, Send, Pend);
  k_scanB<<<32, 256, 0, stream>>>(Send, Pend, Sinit);
  k_scanC<<<NB * KD * NC, 192, 0, stream>>>(Csb, cum, Sinit, ybuf);
  k_out<<<NPOS, 192, 0, stream>>>(ybuf, zs, ln_g, ln_b, Wo, out);
}

// Round 2
// 465.837 us; speedup vs baseline: 2.0555x; 2.0555x over previous
//
#include <hip/hip_runtime.h>

// VMamba mixer forward, MI355X. fp32 throughout.
// B=8, H=W=56 (L=3136), D_MODEL=96, D_INNER=192, DT_RANK=6, HEAD_D=32,
// D_STATE=32, K=4 scan directions. Chunked parallel selective scan, NC=64.

constexpr int DM   = 96;     // D_MODEL
constexpr int DI   = 192;    // D_INNER
constexpr int RK   = 6;      // DT_RANK
constexpr int NS   = 32;     // D_STATE (== HEAD_D)
constexpr int KD   = 4;      // directions
constexpr int HW   = 56;
constexpr int LT   = 3136;   // L = 56*56
constexpr int NB   = 8;      // batch
constexpr int NPOS = NB * LT;   // 25088
constexpr int NC   = 64;     // chunks per sequence
constexpr int CH   = 49;     // chunk length (64*49 = 3136)
constexpr int SEQ = NB * KD; // 32 sequences
constexpr int ELEM = RK * NS * NS;  // 6144 state elements per sequence

__device__ __forceinline__ float siluf(float x) { return x / (1.f + __expf(-x)); }

// sequence index l of direction k  ->  spatial position p (row-major h*56+w)
__device__ __forceinline__ int seq2pos(int k, int l) {
  int m = (k & 2) ? (LT - 1 - l) : l;
  return (k & 1) ? ((m % HW) * HW + m / HW) : m;
}

// ---------------- Kernel 1: in_proj + split + silu(z) ----------------
__global__ __launch_bounds__(384) void k_inproj(const float* __restrict__ x,
                                                const float* __restrict__ Wi,
                                                float* __restrict__ xi,
                                                float* __restrict__ zs) {
  const int PPB = 16;
  __shared__ float sx[PPB][DM];
  int p0 = blockIdx.x * PPB;
  int tid = threadIdx.x;
  for (int i = tid; i < PPB * DM; i += 384) sx[i / DM][i % DM] = x[p0 * DM + i];
  __syncthreads();
  int o = tid;  // output column 0..383
  float acc[PPB];
#pragma unroll
  for (int p = 0; p < PPB; p++) acc[p] = 0.f;
  const float* wr = Wi + o * DM;
  for (int kk = 0; kk < DM; kk++) {
    float w = wr[kk];
#pragma unroll
    for (int p = 0; p < PPB; p++) acc[p] += w * sx[p][kk];
  }
  if (o < DI) {
    for (int p = 0; p < PPB; p++) xi[(p0 + p) * DI + o] = acc[p];
  } else {
    int oz = o - DI;
    for (int p = 0; p < PPB; p++) zs[(p0 + p) * DI + oz] = siluf(acc[p]);
  }
}

// ---------------- Kernel 2: depthwise 3x3 conv + bias + silu ----------------
__global__ void k_conv(const float* __restrict__ xi, const float* __restrict__ cw,
                       const float* __restrict__ cb, float* __restrict__ xc) {
  int t = blockIdx.x * 256 + threadIdx.x;
  if (t >= NPOS * DI) return;
  int c = t % DI;
  int pos = t / DI;
  int p = pos % LT, b = pos / LT;
  int h = p / HW, w = p % HW;
  float acc = cb[c];
#pragma unroll
  for (int dh = 0; dh < 3; dh++) {
    int hh = h + dh - 1;
    if (hh < 0 || hh >= HW) continue;
#pragma unroll
    for (int dw = 0; dw < 3; dw++) {
      int ww = w + dw - 1;
      if (ww < 0 || ww >= HW) continue;
      acc += cw[(dh * 3 + dw) * DI + c] * xi[(b * LT + hh * HW + ww) * DI + c];
    }
  }
  xc[t] = siluf(acc);
}

// ---------------- Kernel 3: x_proj (4 dirs) + softplus/exp ----------------
__global__ __launch_bounds__(320) void k_xproj(const float* __restrict__ xc,
                                               const float* __restrict__ Wp,
                                               const float* __restrict__ A_logs,
                                               const float* __restrict__ dt_bias,
                                               float* __restrict__ dtb,
                                               float* __restrict__ dAb,
                                               float* __restrict__ Bsb,
                                               float* __restrict__ Csb) {
  const int PPB = 8;
  __shared__ float sx[PPB][DI];
  int p0 = blockIdx.x * PPB;
  int tid = threadIdx.x;
  for (int i = tid; i < PPB * DI; i += 320) sx[i / DI][i % DI] = xc[p0 * DI + i];
  __syncthreads();
  if (tid >= 280) return;
  int k = tid / 70, c = tid % 70;
  float acc[PPB];
#pragma unroll
  for (int p = 0; p < PPB; p++) acc[p] = 0.f;
  const float* wr = Wp + tid * DI;  // Wp is [K][70][192] contiguous
  for (int j = 0; j < DI; j++) {
    float w = wr[j];
#pragma unroll
    for (int p = 0; p < PPB; p++) acc[p] += w * sx[p][j];
  }
  if (c < RK) {
    float bias = dt_bias[k * RK + c];
    float Av = -__expf(A_logs[k * RK + c]);
    for (int p = 0; p < PPB; p++) {
      float v = acc[p] + bias;
      float dtv = (v > 20.f) ? v : log1pf(__expf(v));
      int idx = ((p0 + p) * KD + k) * RK + c;
      dtb[idx] = dtv;
      dAb[idx] = __expf(dtv * Av);
    }
  } else if (c < RK + NS) {
    for (int p = 0; p < PPB; p++) Bsb[((p0 + p) * KD + k) * NS + (c - RK)] = acc[p];
  } else {
    for (int p = 0; p < PPB; p++) Csb[((p0 + p) * KD + k) * NS + (c - RK - NS)] = acc[p];
  }
}

// ---------------- Kernel 4: chunked local scan ----------------
// block = 192 threads, thread = (r,d). 2048 blocks = (b,k,chunk).
__global__ __launch_bounds__(192) void k_scanA(const float* __restrict__ xc,
                                               const float* __restrict__ dtb,
                                               const float* __restrict__ dAb,
                                               const float* __restrict__ Bsb,
                                               const float* __restrict__ Csb,
                                               const float* __restrict__ Ds,
                                               float* __restrict__ ybuf,
                                               float* __restrict__ cumdA,
                                               float* __restrict__ Send,
                                               float* __restrict__ Pend) {
  int bi = blockIdx.x;
  int chunk = bi % NC;
  int k = (bi / NC) & 3;
  int b = bi / (NC * KD);
  int tid = threadIdx.x;
  int r = tid >> 5, d = tid & 31;
  __shared__ float sB[2][NS], sC[2][NS], sdA[2][8], sdt[2][8];
  float S[NS];
#pragma unroll
  for (int n = 0; n < NS; n++) S[n] = 0.f;
  float cum = 1.f;
  float Dsv = Ds[(k * RK + r) * NS + d];
  int l0 = chunk * CH;
  {  // prefetch step 0
    int p = seq2pos(k, l0);
    int base = (b * LT + p) * KD + k;
    if (tid < 32) sB[0][tid] = Bsb[base * NS + tid];
    else if (tid < 64) sC[0][tid - 32] = Csb[base * NS + tid - 32];
    else if (tid < 70) sdA[0][tid - 64] = dAb[base * RK + tid - 64];
    else if (tid < 76) sdt[0][tid - 70] = dtb[base * RK + tid - 70];
  }
  for (int l = 0; l < CH; l++) {
    __syncthreads();
    int cur = l & 1;
    if (l + 1 < CH) {  // prefetch next step into other buffer
      int p1 = seq2pos(k, l0 + l + 1);
      int base = (b * LT + p1) * KD + k;
      int nb = cur ^ 1;
      if (tid < 32) sB[nb][tid] = Bsb[base * NS + tid];
      else if (tid < 64) sC[nb][tid - 32] = Csb[base * NS + tid - 32];
      else if (tid < 70) sdA[nb][tid - 64] = dAb[base * RK + tid - 64];
      else if (tid < 76) sdt[nb][tid - 70] = dtb[base * RK + tid - 70];
    }
    int p = seq2pos(k, l0 + l);
    int gbase = b * LT + p;
    float xv = xc[gbase * DI + tid];  // tid == r*32+d == d_inner index
    float dAr = sdA[cur][r], dtr = sdt[cur][r];
    float xdt = xv * dtr;
    float y = 0.f;
#pragma unroll
    for (int n = 0; n < NS; n++) {
      S[n] = S[n] * dAr + xdt * sB[cur][n];
      y += S[n] * sC[cur][n];
    }
    cum *= dAr;
    ybuf[((b * KD + k) * LT + p) * DI + tid] = y + xv * Dsv;
    if (d == 0) cumdA[(gbase * KD + k) * RK + r] = cum;
  }
  int sb = ((b * KD + k) * NC + chunk) * ELEM;
#pragma unroll
  for (int n = 0; n < NS; n++) Send[sb + tid * NS + n] = S[n];
  if (d == 0) Pend[((b * KD + k) * NC + chunk) * RK + r] = cum;
}

// ---------------- Kernel 5: chunk-state combine (in-place exclusive prefix) ----------------
// 196608 independent chains of length NC. After this kernel, Send[c] holds the
// state *entering* chunk c (exclusive prefix).
__global__ __launch_bounds__(256) void k_scanB(float* __restrict__ Send,
                                               const float* __restrict__ Pend) {
  int bi = blockIdx.x;               // 32 seqs * 24 element-tiles
  int seq = bi / (ELEM / 256);
  int e = (bi % (ELEM / 256)) * 256 + threadIdx.x;
  int r = e >> 10;                   // e = r*1024 + d*32 + n
  float run = 0.f;
  for (int c = 0; c < NC; c++) {
    int idx = (seq * NC + c) * ELEM + e;
    float tmp = Send[idx];
    Send[idx] = run;
    run = run * Pend[(seq * NC + c) * RK + r] + tmp;
  }
}

// ---------------- Kernel 6: fixup  y += cumdA * (S_init . C) ----------------
__global__ __launch_bounds__(192) void k_scanC(const float* __restrict__ Csb,
                                               const float* __restrict__ cumdA,
                                               const float* __restrict__ Sinit,
                                               float* __restrict__ ybuf) {
  int bi = blockIdx.x;
  int chunk = bi % NC;
  if (chunk == 0) return;  // S_init == 0
  int k = (bi / NC) & 3;
  int b = bi / (NC * KD);
  int tid = threadIdx.x;
  int r = tid >> 5;
  float S[NS];
  int sb = ((b * KD + k) * NC + chunk) * ELEM;
#pragma unroll
  for (int n = 0; n < NS; n++) S[n] = Sinit[sb + tid * NS + n];
  __shared__ float sC[2][NS], scum[2][8];
  int l0 = chunk * CH;
  {
    int p = seq2pos(k, l0);
    int base = (b * LT + p) * KD + k;
    if (tid < 32) sC[0][tid] = Csb[base * NS + tid];
    else if (tid < 38) scum[0][tid - 32] = cumdA[base * RK + tid - 32];
  }
  for (int l = 0; l < CH; l++) {
    __syncthreads();
    int cur = l & 1;
    if (l + 1 < CH) {
      int p1 = seq2pos(k, l0 + l + 1);
      int base = (b * LT + p1) * KD + k;
      int nb = cur ^ 1;
      if (tid < 32) sC[nb][tid] = Csb[base * NS + tid];
      else if (tid < 38) scum[nb][tid - 32] = cumdA[base * RK + tid - 32];
    }
    float y = 0.f;
#pragma unroll
    for (int n = 0; n < NS; n++) y += S[n] * sC[cur][n];
    int p = seq2pos(k, l0 + l);
    ybuf[((b * KD + k) * LT + p) * DI + tid] += y * scum[cur][r];
  }
}

// ---------------- Kernel 7: merge + LN + gelu + *silu(z) + out_proj ----------------
// 4 positions per block; Wo row segment loaded once, reused 4x.
__global__ __launch_bounds__(192) void k_out(const float* __restrict__ ybuf,
                                             const float* __restrict__ zs,
                                             const float* __restrict__ ln_g,
                                             const float* __restrict__ ln_b,
                                             const float* __restrict__ Wo,
                                             float* __restrict__ out) {
  const int PP = 4;
  int pos0 = blockIdx.x * PP;  // b*LT + p, all PP positions in same b (LT%4==0)
  int b = pos0 / LT, p0 = pos0 % LT;
  int tid = threadIdx.x;  // 0..191 = channel
  float v[PP], s1[PP], s2[PP];
#pragma unroll
  for (int q = 0; q < PP; q++) {
    float acc = 0.f;
#pragma unroll
    for (int k = 0; k < KD; k++) acc += ybuf[((b * KD + k) * LT + p0 + q) * DI + tid];
    v[q] = acc; s1[q] = acc; s2[q] = acc * acc;
  }
#pragma unroll
  for (int off = 32; off; off >>= 1) {
#pragma unroll
    for (int q = 0; q < PP; q++) {
      s1[q] += __shfl_down(s1[q], off, 64);
      s2[q] += __shfl_down(s2[q], off, 64);
    }
  }
  __shared__ float rs1[3][PP], rs2[3][PP];
  int wave = tid >> 6, lane = tid & 63;
  if (lane == 0) {
#pragma unroll
    for (int q = 0; q < PP; q++) { rs1[wave][q] = s1[q]; rs2[wave][q] = s2[q]; }
  }
  __syncthreads();
  __shared__ float su[PP][DI];
  float g = ln_g[tid], be = ln_b[tid];
#pragma unroll
  for (int q = 0; q < PP; q++) {
    float mean = (rs1[0][q] + rs1[1][q] + rs1[2][q]) * (1.f / 192.f);
    float var = (rs2[0][q] + rs2[1][q] + rs2[2][q]) * (1.f / 192.f) - mean * mean;
    float rstd = rsqrtf(var + 1e-5f);
    float t = (v[q] - mean) * rstd * g + be;
    float ge = 0.5f * t * (1.f + erff(t * 0.70710678118f));
    su[q][tid] = ge * zs[(pos0 + q) * DI + tid];
  }
  __syncthreads();
  int o = tid % DM, half = tid / DM;  // 2 threads per output column
  const float* wr = Wo + o * DI + half * DM;
  float acc[PP];
#pragma unroll
  for (int q = 0; q < PP; q++) acc[q] = 0.f;
  for (int j = 0; j < DM; j++) {
    float w = wr[j];
#pragma unroll
    for (int q = 0; q < PP; q++) acc[q] += w * su[q][half * DM + j];
  }
  __shared__ float part[PP][DI];
#pragma unroll
  for (int q = 0; q < PP; q++) part[q][tid] = acc[q];
  __syncthreads();
  if (tid < DM) {
#pragma unroll
    for (int q = 0; q < PP; q++)
      out[(pos0 + q) * DM + tid] = part[q][tid] + part[q][tid + DM];
  }
}

extern "C" void kernel_launch(void* const* d_in, const int* in_sizes, int n_in,
                              void* d_out, int out_size, void* d_ws, size_t ws_size,
                              hipStream_t stream) {
  const float* x       = (const float*)d_in[0];
  const float* Wi      = (const float*)d_in[1];
  const float* cw      = (const float*)d_in[2];
  const float* cb      = (const float*)d_in[3];
  const float* Wp      = (const float*)d_in[4];
  const float* Ds      = (const float*)d_in[5];
  const float* A_logs  = (const float*)d_in[6];
  const float* dt_bias = (const float*)d_in[7];
  const float* ln_g    = (const float*)d_in[8];
  const float* ln_b    = (const float*)d_in[9];
  const float* Wo      = (const float*)d_in[10];
  float* out = (float*)d_out;

  float* ws = (float*)d_ws;
  float* xi    = ws;                       // NPOS*DI
  float* zs    = xi + (size_t)NPOS * DI;
  float* xc    = zs + (size_t)NPOS * DI;
  float* dtb   = xc + (size_t)NPOS * DI;   // NPOS*KD*RK
  float* dAb   = dtb + (size_t)NPOS * KD * RK;
  float* Bsb   = dAb + (size_t)NPOS * KD * RK;   // NPOS*KD*NS
  float* Csb   = Bsb + (size_t)NPOS * KD * NS;
  float* cum   = Csb + (size_t)NPOS * KD * NS;   // NPOS*KD*RK
  float* ybuf  = cum + (size_t)NPOS * KD * RK;   // NB*KD*LT*DI
  float* Send  = ybuf + (size_t)NB * KD * LT * DI;  // SEQ*NC*ELEM (in-place prefix)
  float* Pend  = Send + (size_t)SEQ * NC * ELEM;    // SEQ*NC*RK

  k_inproj<<<NPOS / 16, 384, 0, stream>>>(x, Wi, xi, zs);
  k_conv<<<(NPOS * DI + 255) / 256, 256, 0, stream>>>(xi, cw, cb, xc);
  k_xproj<<<NPOS / 8, 320, 0, stream>>>(xc, Wp, A_logs, dt_bias, dtb, dAb, Bsb, Csb);
  k_scanA<<<NB * KD * NC, 192, 0, stream>>>(xc, dtb, dAb, Bsb, Csb, Ds, ybuf, cum, Send, Pend);
  k_scanB<<<SEQ * (ELEM / 256), 256, 0, stream>>>(Send, Pend);
  k_scanC<<<NB * KD * NC, 192, 0, stream>>>(Csb, cum, Send, ybuf);
  k_out<<<NPOS / 4, 192, 0, stream>>>(ybuf, zs, ln_g, ln_b, Wo, out);
}

// Round 3
// 400.279 us; speedup vs baseline: 2.3922x; 1.1638x over previous
//
#include <hip/hip_runtime.h>

// VMamba mixer forward, MI355X. fp32 + bf16-MFMA x_proj.
// B=8, H=W=56 (L=3136), D_MODEL=96, D_INNER=192, DT_RANK=6, HEAD_D=32,
// D_STATE=32, K=4 scan directions. Chunked parallel selective scan, NC=64.

constexpr int DM   = 96;     // D_MODEL
constexpr int DI   = 192;    // D_INNER
constexpr int RK   = 6;      // DT_RANK
constexpr int NS   = 32;     // D_STATE (== HEAD_D)
constexpr int KD   = 4;      // directions
constexpr int HW   = 56;
constexpr int LT   = 3136;   // L = 56*56
constexpr int NB   = 8;      // batch
constexpr int NPOS = NB * LT;   // 25088
constexpr int NC   = 64;     // chunks per sequence
constexpr int CH   = 49;     // chunk length (64*49 = 3136)
constexpr int SEQ = NB * KD; // 32 sequences
constexpr int ELEM = RK * NS * NS;  // 6144 state elements per sequence
constexpr int NO   = 280;    // x_proj outputs (4*70)
constexpr int NOP  = 288;    // padded to 18 MFMA n-tiles

typedef __attribute__((ext_vector_type(8))) __bf16 bf16x8;
typedef __attribute__((ext_vector_type(4))) float f32x4;

__device__ __forceinline__ float siluf(float x) { return x / (1.f + __expf(-x)); }

__device__ __forceinline__ unsigned short f2bf(float f) {  // RNE, finite inputs
  unsigned int u = __float_as_uint(f);
  u = (u + 0x7fffu + ((u >> 16) & 1u)) >> 16;
  return (unsigned short)u;
}

// sequence index l of direction k  ->  spatial position p (row-major h*56+w)
__device__ __forceinline__ int seq2pos(int k, int l) {
  int m = (k & 2) ? (LT - 1 - l) : l;
  return (k & 1) ? ((m % HW) * HW + m / HW) : m;
}

// ---------------- Kernel 1: in_proj + split + silu(z) ----------------
__global__ __launch_bounds__(384) void k_inproj(const float* __restrict__ x,
                                                const float* __restrict__ Wi,
                                                float* __restrict__ xi,
                                                float* __restrict__ zs) {
  const int PPB = 16;
  __shared__ float sx[PPB][DM];
  int p0 = blockIdx.x * PPB;
  int tid = threadIdx.x;
  for (int i = tid; i < PPB * DM; i += 384) sx[i / DM][i % DM] = x[p0 * DM + i];
  __syncthreads();
  int o = tid;  // output column 0..383
  float acc[PPB];
#pragma unroll
  for (int p = 0; p < PPB; p++) acc[p] = 0.f;
  const float* wr = Wi + o * DM;
  for (int kk = 0; kk < DM; kk++) {
    float w = wr[kk];
#pragma unroll
    for (int p = 0; p < PPB; p++) acc[p] += w * sx[p][kk];
  }
  if (o < DI) {
    for (int p = 0; p < PPB; p++) xi[(p0 + p) * DI + o] = acc[p];
  } else {
    int oz = o - DI;
    for (int p = 0; p < PPB; p++) zs[(p0 + p) * DI + oz] = siluf(acc[p]);
  }
}

// ---------------- Kernel 2: depthwise 3x3 conv + bias + silu (+bf16 copy) ----
__global__ void k_conv(const float* __restrict__ xi, const float* __restrict__ cw,
                       const float* __restrict__ cb, float* __restrict__ xc,
                       unsigned short* __restrict__ xcb) {
  int t = blockIdx.x * 256 + threadIdx.x;
  if (t >= NPOS * DI) return;
  int c = t % DI;
  int pos = t / DI;
  int p = pos % LT, b = pos / LT;
  int h = p / HW, w = p % HW;
  float acc = cb[c];
#pragma unroll
  for (int dh = 0; dh < 3; dh++) {
    int hh = h + dh - 1;
    if (hh < 0 || hh >= HW) continue;
#pragma unroll
    for (int dw = 0; dw < 3; dw++) {
      int ww = w + dw - 1;
      if (ww < 0 || ww >= HW) continue;
      acc += cw[(dh * 3 + dw) * DI + c] * xi[(b * LT + hh * HW + ww) * DI + c];
    }
  }
  float v = siluf(acc);
  xc[t] = v;
  xcb[t] = f2bf(v);
}

// ---------------- Kernel 2b: Wp -> bf16, padded to 288 rows ----------------
__global__ __launch_bounds__(256) void k_wprep(const float* __restrict__ Wp,
                                               unsigned short* __restrict__ Wpb) {
  int t = blockIdx.x * 256 + threadIdx.x;
  if (t >= NOP * DI) return;
  int o = t / DI;
  Wpb[t] = (o < NO) ? f2bf(Wp[t]) : (unsigned short)0;
}

// ---------------- Kernel 3: x_proj via bf16 MFMA + softplus/exp ----------------
// Wave = 16 positions; 18 n-tiles cover 288 (280 real) outputs; K=192 in 6 steps.
__global__ __launch_bounds__(128) void k_xproj(const unsigned short* __restrict__ xcb,
                                               const unsigned short* __restrict__ Wpb,
                                               const float* __restrict__ A_logs,
                                               const float* __restrict__ dt_bias,
                                               float* __restrict__ dtb,
                                               float* __restrict__ dAb,
                                               float* __restrict__ Bsb,
                                               float* __restrict__ Csb) {
  int wid = threadIdx.x >> 6;
  int lane = threadIdx.x & 63;
  int pos0 = blockIdx.x * 32 + wid * 16;
  int lrow = lane & 15;   // A: position-in-tile, B: output-in-tile
  int lgrp = lane >> 4;   // k-group (8 bf16 each)
  bf16x8 a[6];
  const unsigned short* arow = xcb + (size_t)(pos0 + lrow) * DI + lgrp * 8;
#pragma unroll
  for (int ks = 0; ks < 6; ks++)
    a[ks] = *reinterpret_cast<const bf16x8*>(arow + ks * 32);
  f32x4 acc[18];
#pragma unroll
  for (int t = 0; t < 18; t++) acc[t] = (f32x4){0.f, 0.f, 0.f, 0.f};
  const unsigned short* brow = Wpb + (size_t)lrow * DI + lgrp * 8;
#pragma unroll
  for (int ks = 0; ks < 6; ks++) {
#pragma unroll
    for (int ot = 0; ot < 18; ot++) {
      bf16x8 bf = *reinterpret_cast<const bf16x8*>(brow + (size_t)ot * 16 * DI + ks * 32);
      acc[ot] = __builtin_amdgcn_mfma_f32_16x16x32_bf16(a[ks], bf, acc[ot], 0, 0, 0);
    }
  }
  // epilogue: C/D layout col=lane&15 (output), row=(lane>>4)*4+reg (position)
#pragma unroll
  for (int ot = 0; ot < 18; ot++) {
    int o = ot * 16 + lrow;
    if (o >= NO) continue;
    int k = o / 70, c = o % 70;
#pragma unroll
    for (int r = 0; r < 4; r++) {
      int pos = pos0 + lgrp * 4 + r;
      float v = acc[ot][r];
      int base = pos * KD + k;
      if (c < RK) {
        float bias = dt_bias[k * RK + c];
        float Av = -__expf(A_logs[k * RK + c]);
        float s = v + bias;
        float dtv = (s > 20.f) ? s : log1pf(__expf(s));
        dtb[base * RK + c] = dtv;
        dAb[base * RK + c] = __expf(dtv * Av);
      } else if (c < RK + NS) {
        Bsb[base * NS + (c - RK)] = v;
      } else {
        Csb[base * NS + (c - RK - NS)] = v;
      }
    }
  }
}

// ---------------- Kernel 4: chunked local scan ----------------
__global__ __launch_bounds__(192) void k_scanA(const float* __restrict__ xc,
                                               const float* __restrict__ dtb,
                                               const float* __restrict__ dAb,
                                               const float* __restrict__ Bsb,
                                               const float* __restrict__ Csb,
                                               const float* __restrict__ Ds,
                                               float* __restrict__ ybuf,
                                               float* __restrict__ cumdA,
                                               float* __restrict__ Send,
                                               float* __restrict__ Pend) {
  int bi = blockIdx.x;
  int chunk = bi % NC;
  int k = (bi / NC) & 3;
  int b = bi / (NC * KD);
  int tid = threadIdx.x;
  int r = tid >> 5, d = tid & 31;
  __shared__ float sB[2][NS], sC[2][NS], sdA[2][8], sdt[2][8];
  float S[NS];
#pragma unroll
  for (int n = 0; n < NS; n++) S[n] = 0.f;
  float cum = 1.f;
  float Dsv = Ds[(k * RK + r) * NS + d];
  int l0 = chunk * CH;
  {  // prefetch step 0
    int p = seq2pos(k, l0);
    int base = (b * LT + p) * KD + k;
    if (tid < 32) sB[0][tid] = Bsb[base * NS + tid];
    else if (tid < 64) sC[0][tid - 32] = Csb[base * NS + tid - 32];
    else if (tid < 70) sdA[0][tid - 64] = dAb[base * RK + tid - 64];
    else if (tid < 76) sdt[0][tid - 70] = dtb[base * RK + tid - 70];
  }
  for (int l = 0; l < CH; l++) {
    __syncthreads();
    int cur = l & 1;
    if (l + 1 < CH) {
      int p1 = seq2pos(k, l0 + l + 1);
      int base = (b * LT + p1) * KD + k;
      int nb = cur ^ 1;
      if (tid < 32) sB[nb][tid] = Bsb[base * NS + tid];
      else if (tid < 64) sC[nb][tid - 32] = Csb[base * NS + tid - 32];
      else if (tid < 70) sdA[nb][tid - 64] = dAb[base * RK + tid - 64];
      else if (tid < 76) sdt[nb][tid - 70] = dtb[base * RK + tid - 70];
    }
    int p = seq2pos(k, l0 + l);
    int gbase = b * LT + p;
    float xv = xc[gbase * DI + tid];
    float dAr = sdA[cur][r], dtr = sdt[cur][r];
    float xdt = xv * dtr;
    float y = 0.f;
#pragma unroll
    for (int n = 0; n < NS; n++) {
      S[n] = S[n] * dAr + xdt * sB[cur][n];
      y += S[n] * sC[cur][n];
    }
    cum *= dAr;
    ybuf[((b * KD + k) * LT + p) * DI + tid] = y + xv * Dsv;
    if (d == 0) cumdA[(gbase * KD + k) * RK + r] = cum;
  }
  int sb = ((b * KD + k) * NC + chunk) * ELEM;
#pragma unroll
  for (int n = 0; n < NS; n++) Send[sb + tid * NS + n] = S[n];
  if (d == 0) Pend[((b * KD + k) * NC + chunk) * RK + r] = cum;
}

// ---------------- Kernel 5: chunk-state combine (in-place exclusive prefix) ----
__global__ __launch_bounds__(256) void k_scanB(float* __restrict__ Send,
                                               const float* __restrict__ Pend) {
  int bi = blockIdx.x;               // 32 seqs * 24 element-tiles
  int seq = bi / (ELEM / 256);
  int e = (bi % (ELEM / 256)) * 256 + threadIdx.x;
  int r = e >> 10;                   // e = r*1024 + d*32 + n
  float run = 0.f;
  for (int c = 0; c < NC; c++) {
    int idx = (seq * NC + c) * ELEM + e;
    float tmp = Send[idx];
    Send[idx] = run;
    run = run * Pend[(seq * NC + c) * RK + r] + tmp;
  }
}

// ---------------- Kernel 6: fixup  y += cumdA * (S_init . C) ----------------
__global__ __launch_bounds__(192) void k_scanC(const float* __restrict__ Csb,
                                               const float* __restrict__ cumdA,
                                               const float* __restrict__ Sinit,
                                               float* __restrict__ ybuf) {
  int bi = blockIdx.x;
  int chunk = bi % NC;
  if (chunk == 0) return;  // S_init == 0
  int k = (bi / NC) & 3;
  int b = bi / (NC * KD);
  int tid = threadIdx.x;
  int r = tid >> 5;
  float S[NS];
  int sb = ((b * KD + k) * NC + chunk) * ELEM;
#pragma unroll
  for (int n = 0; n < NS; n++) S[n] = Sinit[sb + tid * NS + n];
  __shared__ float sC[2][NS], scum[2][8];
  int l0 = chunk * CH;
  {
    int p = seq2pos(k, l0);
    int base = (b * LT + p) * KD + k;
    if (tid < 32) sC[0][tid] = Csb[base * NS + tid];
    else if (tid < 38) scum[0][tid - 32] = cumdA[base * RK + tid - 32];
  }
  for (int l = 0; l < CH; l++) {
    __syncthreads();
    int cur = l & 1;
    if (l + 1 < CH) {
      int p1 = seq2pos(k, l0 + l + 1);
      int base = (b * LT + p1) * KD + k;
      int nb = cur ^ 1;
      if (tid < 32) sC[nb][tid] = Csb[base * NS + tid];
      else if (tid < 38) scum[nb][tid - 32] = cumdA[base * RK + tid - 32];
    }
    float y = 0.f;
#pragma unroll
    for (int n = 0; n < NS; n++) y += S[n] * sC[cur][n];
    int p = seq2pos(k, l0 + l);
    ybuf[((b * KD + k) * LT + p) * DI + tid] += y * scum[cur][r];
  }
}

// ---------------- Kernel 7: merge + LN + gelu + *silu(z) + out_proj ----------------
__global__ __launch_bounds__(192) void k_out(const float* __restrict__ ybuf,
                                             const float* __restrict__ zs,
                                             const float* __restrict__ ln_g,
                                             const float* __restrict__ ln_b,
                                             const float* __restrict__ Wo,
                                             float* __restrict__ out) {
  const int PP = 4;
  int pos0 = blockIdx.x * PP;
  int b = pos0 / LT, p0 = pos0 % LT;
  int tid = threadIdx.x;  // 0..191 = channel
  float v[PP], s1[PP], s2[PP];
#pragma unroll
  for (int q = 0; q < PP; q++) {
    float acc = 0.f;
#pragma unroll
    for (int k = 0; k < KD; k++) acc += ybuf[((b * KD + k) * LT + p0 + q) * DI + tid];
    v[q] = acc; s1[q] = acc; s2[q] = acc * acc;
  }
#pragma unroll
  for (int off = 32; off; off >>= 1) {
#pragma unroll
    for (int q = 0; q < PP; q++) {
      s1[q] += __shfl_down(s1[q], off, 64);
      s2[q] += __shfl_down(s2[q], off, 64);
    }
  }
  __shared__ float rs1[3][PP], rs2[3][PP];
  int wave = tid >> 6, lane = tid & 63;
  if (lane == 0) {
#pragma unroll
    for (int q = 0; q < PP; q++) { rs1[wave][q] = s1[q]; rs2[wave][q] = s2[q]; }
  }
  __syncthreads();
  __shared__ float su[PP][DI];
  float g = ln_g[tid], be = ln_b[tid];
#pragma unroll
  for (int q = 0; q < PP; q++) {
    float mean = (rs1[0][q] + rs1[1][q] + rs1[2][q]) * (1.f / 192.f);
    float var = (rs2[0][q] + rs2[1][q] + rs2[2][q]) * (1.f / 192.f) - mean * mean;
    float rstd = rsqrtf(var + 1e-5f);
    float t = (v[q] - mean) * rstd * g + be;
    float ge = 0.5f * t * (1.f + erff(t * 0.70710678118f));
    su[q][tid] = ge * zs[(pos0 + q) * DI + tid];
  }
  __syncthreads();
  int o = tid % DM, half = tid / DM;
  const float* wr = Wo + o * DI + half * DM;
  float acc[PP];
#pragma unroll
  for (int q = 0; q < PP; q++) acc[q] = 0.f;
  for (int j = 0; j < DM; j++) {
    float w = wr[j];
#pragma unroll
    for (int q = 0; q < PP; q++) acc[q] += w * su[q][half * DM + j];
  }
  __shared__ float part[PP][DI];
#pragma unroll
  for (int q = 0; q < PP; q++) part[q][tid] = acc[q];
  __syncthreads();
  if (tid < DM) {
#pragma unroll
    for (int q = 0; q < PP; q++)
      out[(pos0 + q) * DM + tid] = part[q][tid] + part[q][tid + DM];
  }
}

extern "C" void kernel_launch(void* const* d_in, const int* in_sizes, int n_in,
                              void* d_out, int out_size, void* d_ws, size_t ws_size,
                              hipStream_t stream) {
  const float* x       = (const float*)d_in[0];
  const float* Wi      = (const float*)d_in[1];
  const float* cw      = (const float*)d_in[2];
  const float* cb      = (const float*)d_in[3];
  const float* Wp      = (const float*)d_in[4];
  const float* Ds      = (const float*)d_in[5];
  const float* A_logs  = (const float*)d_in[6];
  const float* dt_bias = (const float*)d_in[7];
  const float* ln_g    = (const float*)d_in[8];
  const float* ln_b    = (const float*)d_in[9];
  const float* Wo      = (const float*)d_in[10];
  float* out = (float*)d_out;

  float* ws = (float*)d_ws;
  float* xi    = ws;                       // NPOS*DI
  float* zs    = xi + (size_t)NPOS * DI;
  float* xc    = zs + (size_t)NPOS * DI;
  float* dtb   = xc + (size_t)NPOS * DI;   // NPOS*KD*RK
  float* dAb   = dtb + (size_t)NPOS * KD * RK;
  float* Bsb   = dAb + (size_t)NPOS * KD * RK;   // NPOS*KD*NS
  float* Csb   = Bsb + (size_t)NPOS * KD * NS;
  float* cum   = Csb + (size_t)NPOS * KD * NS;   // NPOS*KD*RK
  float* ybuf  = cum + (size_t)NPOS * KD * RK;   // NB*KD*LT*DI
  float* Send  = ybuf + (size_t)NB * KD * LT * DI;  // SEQ*NC*ELEM (in-place prefix)
  float* Pend  = Send + (size_t)SEQ * NC * ELEM;    // SEQ*NC*RK
  float* WpbF  = Pend + (size_t)SEQ * NC * RK;      // NOP*DI bf16 = NOP*DI/2 floats
  // xcb (bf16 conv copy) aliases Send: dead until scanA overwrites it.
  unsigned short* xcb = (unsigned short*)Send;
  unsigned short* Wpb = (unsigned short*)WpbF;

  k_inproj<<<NPOS / 16, 384, 0, stream>>>(x, Wi, xi, zs);
  k_conv<<<(NPOS * DI + 255) / 256, 256, 0, stream>>>(xi, cw, cb, xc, xcb);
  k_wprep<<<(NOP * DI + 255) / 256, 256, 0, stream>>>(Wp, Wpb);
  k_xproj<<<NPOS / 32, 128, 0, stream>>>(xcb, Wpb, A_logs, dt_bias, dtb, dAb, Bsb, Csb);
  k_scanA<<<NB * KD * NC, 192, 0, stream>>>(xc, dtb, dAb, Bsb, Csb, Ds, ybuf, cum, Send, Pend);
  k_scanB<<<SEQ * (ELEM / 256), 256, 0, stream>>>(Send, Pend);
  k_scanC<<<NB * KD * NC, 192, 0, stream>>>(Csb, cum, Send, ybuf);
  k_out<<<NPOS / 4, 192, 0, stream>>>(ybuf, zs, ln_g, ln_b, Wo, out);
}

// Round 4
// 357.285 us; speedup vs baseline: 2.6800x; 1.1203x over previous
//
#include <hip/hip_runtime.h>

// VMamba mixer forward, MI355X. fp32 + bf16-MFMA x_proj.
// Barrier-free selective scan: B/C/dA/dt are block-uniform per step ->
// load from global (L1/L2 broadcast), no LDS, no __syncthreads.

constexpr int DM   = 96;     // D_MODEL
constexpr int DI   = 192;    // D_INNER
constexpr int RK   = 6;      // DT_RANK
constexpr int NS   = 32;     // D_STATE (== HEAD_D)
constexpr int KD   = 4;      // directions
constexpr int HW   = 56;
constexpr int LT   = 3136;   // L = 56*56
constexpr int NB   = 8;      // batch
constexpr int NPOS = NB * LT;   // 25088
constexpr int NC   = 64;     // chunks per sequence
constexpr int CH   = 49;     // chunk length (64*49 = 3136)
constexpr int SEQ = NB * KD; // 32 sequences
constexpr int ELEM = RK * NS * NS;  // 6144 state elements per sequence
constexpr int NO   = 280;    // x_proj outputs (4*70)
constexpr int NOP  = 288;    // padded to 18 MFMA n-tiles

typedef __attribute__((ext_vector_type(8))) __bf16 bf16x8;
typedef __attribute__((ext_vector_type(4))) float f32x4;

__device__ __forceinline__ float siluf(float x) { return x / (1.f + __expf(-x)); }

__device__ __forceinline__ unsigned short f2bf(float f) {  // RNE, finite inputs
  unsigned int u = __float_as_uint(f);
  u = (u + 0x7fffu + ((u >> 16) & 1u)) >> 16;
  return (unsigned short)u;
}

// sequence index l of direction k  ->  spatial position p (row-major h*56+w)
__device__ __forceinline__ int seq2pos(int k, int l) {
  int m = (k & 2) ? (LT - 1 - l) : l;
  return (k & 1) ? ((m % HW) * HW + m / HW) : m;
}

// ---------------- Kernel 1: in_proj + split + silu(z) ----------------
__global__ __launch_bounds__(384) void k_inproj(const float* __restrict__ x,
                                                const float* __restrict__ Wi,
                                                float* __restrict__ xi,
                                                float* __restrict__ zs) {
  const int PPB = 16;
  __shared__ float sx[PPB][DM];
  int p0 = blockIdx.x * PPB;
  int tid = threadIdx.x;
  for (int i = tid; i < PPB * DM; i += 384) sx[i / DM][i % DM] = x[p0 * DM + i];
  __syncthreads();
  int o = tid;  // output column 0..383
  float acc[PPB];
#pragma unroll
  for (int p = 0; p < PPB; p++) acc[p] = 0.f;
  const float* wr = Wi + o * DM;
  for (int kk = 0; kk < DM; kk++) {
    float w = wr[kk];
#pragma unroll
    for (int p = 0; p < PPB; p++) acc[p] += w * sx[p][kk];
  }
  if (o < DI) {
    for (int p = 0; p < PPB; p++) xi[(p0 + p) * DI + o] = acc[p];
  } else {
    int oz = o - DI;
    for (int p = 0; p < PPB; p++) zs[(p0 + p) * DI + oz] = siluf(acc[p]);
  }
}

// ---------------- Kernel 2: depthwise 3x3 conv + bias + silu (+bf16 copy) ----
__global__ void k_conv(const float* __restrict__ xi, const float* __restrict__ cw,
                       const float* __restrict__ cb, float* __restrict__ xc,
                       unsigned short* __restrict__ xcb) {
  int t = blockIdx.x * 256 + threadIdx.x;
  if (t >= NPOS * DI) return;
  int c = t % DI;
  int pos = t / DI;
  int p = pos % LT, b = pos / LT;
  int h = p / HW, w = p % HW;
  float acc = cb[c];
#pragma unroll
  for (int dh = 0; dh < 3; dh++) {
    int hh = h + dh - 1;
    if (hh < 0 || hh >= HW) continue;
#pragma unroll
    for (int dw = 0; dw < 3; dw++) {
      int ww = w + dw - 1;
      if (ww < 0 || ww >= HW) continue;
      acc += cw[(dh * 3 + dw) * DI + c] * xi[(b * LT + hh * HW + ww) * DI + c];
    }
  }
  float v = siluf(acc);
  xc[t] = v;
  xcb[t] = f2bf(v);
}

// ---------------- Kernel 2b: Wp -> bf16, padded to 288 rows ----------------
__global__ __launch_bounds__(256) void k_wprep(const float* __restrict__ Wp,
                                               unsigned short* __restrict__ Wpb) {
  int t = blockIdx.x * 256 + threadIdx.x;
  if (t >= NOP * DI) return;
  int o = t / DI;
  Wpb[t] = (o < NO) ? f2bf(Wp[t]) : (unsigned short)0;
}

// ---------------- Kernel 3: x_proj via bf16 MFMA + softplus/exp ----------------
__global__ __launch_bounds__(128) void k_xproj(const unsigned short* __restrict__ xcb,
                                               const unsigned short* __restrict__ Wpb,
                                               const float* __restrict__ A_logs,
                                               const float* __restrict__ dt_bias,
                                               float* __restrict__ dtb,
                                               float* __restrict__ dAb,
                                               float* __restrict__ Bsb,
                                               float* __restrict__ Csb) {
  int wid = threadIdx.x >> 6;
  int lane = threadIdx.x & 63;
  int pos0 = blockIdx.x * 32 + wid * 16;
  int lrow = lane & 15;   // A: position-in-tile, B: output-in-tile
  int lgrp = lane >> 4;   // k-group (8 bf16 each)
  bf16x8 a[6];
  const unsigned short* arow = xcb + (size_t)(pos0 + lrow) * DI + lgrp * 8;
#pragma unroll
  for (int ks = 0; ks < 6; ks++)
    a[ks] = *reinterpret_cast<const bf16x8*>(arow + ks * 32);
  f32x4 acc[18];
#pragma unroll
  for (int t = 0; t < 18; t++) acc[t] = (f32x4){0.f, 0.f, 0.f, 0.f};
  const unsigned short* brow = Wpb + (size_t)lrow * DI + lgrp * 8;
#pragma unroll
  for (int ks = 0; ks < 6; ks++) {
#pragma unroll
    for (int ot = 0; ot < 18; ot++) {
      bf16x8 bf = *reinterpret_cast<const bf16x8*>(brow + (size_t)ot * 16 * DI + ks * 32);
      acc[ot] = __builtin_amdgcn_mfma_f32_16x16x32_bf16(a[ks], bf, acc[ot], 0, 0, 0);
    }
  }
#pragma unroll
  for (int ot = 0; ot < 18; ot++) {
    int o = ot * 16 + lrow;
    if (o >= NO) continue;
    int k = o / 70, c = o % 70;
#pragma unroll
    for (int r = 0; r < 4; r++) {
      int pos = pos0 + lgrp * 4 + r;
      float v = acc[ot][r];
      int base = pos * KD + k;
      if (c < RK) {
        float bias = dt_bias[k * RK + c];
        float Av = -__expf(A_logs[k * RK + c]);
        float s = v + bias;
        float dtv = (s > 20.f) ? s : log1pf(__expf(s));
        dtb[base * RK + c] = dtv;
        dAb[base * RK + c] = __expf(dtv * Av);
      } else if (c < RK + NS) {
        Bsb[base * NS + (c - RK)] = v;
      } else {
        Csb[base * NS + (c - RK - NS)] = v;
      }
    }
  }
}

// ---------------- Kernel 4: chunked local scan (barrier-free) ----------------
// block = 192 threads, thread = (r,d). 2048 blocks = (b,k,chunk).
__global__ __launch_bounds__(192) void k_scanA(const float* __restrict__ xc,
                                               const float* __restrict__ dtb,
                                               const float* __restrict__ dAb,
                                               const float* __restrict__ Bsb,
                                               const float* __restrict__ Csb,
                                               const float* __restrict__ Ds,
                                               float* __restrict__ ybuf,
                                               float* __restrict__ cumdA,
                                               float* __restrict__ Send,
                                               float* __restrict__ Pend) {
  int bi = blockIdx.x;
  int chunk = bi % NC;
  int k = (bi / NC) & 3;
  int b = bi / (NC * KD);
  int tid = threadIdx.x;
  int r = tid >> 5, d = tid & 31;
  float S[NS];
#pragma unroll
  for (int n = 0; n < NS; n++) S[n] = 0.f;
  float cum = 1.f;
  float Dsv = Ds[(k * RK + r) * NS + d];
  int l0 = chunk * CH;
  for (int l = 0; l < CH; l++) {
    int p = seq2pos(k, l0 + l);
    int gbase = b * LT + p;
    int base = gbase * KD + k;          // block-uniform
    const f32x4* Bp = reinterpret_cast<const f32x4*>(Bsb + (size_t)base * NS);
    const f32x4* Cp = reinterpret_cast<const f32x4*>(Csb + (size_t)base * NS);
    f32x4 bv[8], cv[8];
#pragma unroll
    for (int i = 0; i < 8; i++) { bv[i] = Bp[i]; cv[i] = Cp[i]; }
    float dAr = dAb[base * RK + r];
    float dtr = dtb[base * RK + r];
    float xv = xc[gbase * DI + tid];
    float xdt = xv * dtr;
    float y = 0.f;
#pragma unroll
    for (int i = 0; i < 8; i++) {
#pragma unroll
      for (int j = 0; j < 4; j++) {
        int n = i * 4 + j;
        S[n] = S[n] * dAr + xdt * bv[i][j];
        y += S[n] * cv[i][j];
      }
    }
    cum *= dAr;
    ybuf[((b * KD + k) * LT + p) * DI + tid] = y + xv * Dsv;
    if (d == 0) cumdA[base * RK + r] = cum;
  }
  int sb = ((b * KD + k) * NC + chunk) * ELEM;
#pragma unroll
  for (int n = 0; n < NS; n++) Send[sb + tid * NS + n] = S[n];
  if (d == 0) Pend[((b * KD + k) * NC + chunk) * RK + r] = cum;
}

// ---------------- Kernel 5: chunk-state combine (in-place exclusive prefix) ----
__global__ __launch_bounds__(256) void k_scanB(float* __restrict__ Send,
                                               const float* __restrict__ Pend) {
  int bi = blockIdx.x;               // 32 seqs * 24 element-tiles
  int seq = bi / (ELEM / 256);
  int e = (bi % (ELEM / 256)) * 256 + threadIdx.x;
  int r = e >> 10;                   // e = r*1024 + d*32 + n
  float run = 0.f;
  for (int c = 0; c < NC; c++) {
    int idx = (seq * NC + c) * ELEM + e;
    float tmp = Send[idx];
    Send[idx] = run;
    run = run * Pend[(seq * NC + c) * RK + r] + tmp;
  }
}

// ---------------- Kernel 6: fixup  y += cumdA * (S_init . C)  (barrier-free) ----
__global__ __launch_bounds__(192) void k_scanC(const float* __restrict__ Csb,
                                               const float* __restrict__ cumdA,
                                               const float* __restrict__ Sinit,
                                               float* __restrict__ ybuf) {
  int bi = blockIdx.x;
  int chunk = bi % NC;
  if (chunk == 0) return;  // S_init == 0
  int k = (bi / NC) & 3;
  int b = bi / (NC * KD);
  int tid = threadIdx.x;
  int r = tid >> 5;
  float S[NS];
  int sb = ((b * KD + k) * NC + chunk) * ELEM;
#pragma unroll
  for (int n = 0; n < NS; n++) S[n] = Sinit[sb + tid * NS + n];
  int l0 = chunk * CH;
  for (int l = 0; l < CH; l++) {
    int p = seq2pos(k, l0 + l);
    int base = (b * LT + p) * KD + k;  // block-uniform
    const f32x4* Cp = reinterpret_cast<const f32x4*>(Csb + (size_t)base * NS);
    f32x4 cv[8];
#pragma unroll
    for (int i = 0; i < 8; i++) cv[i] = Cp[i];
    float cumv = cumdA[base * RK + r];
    float y = 0.f;
#pragma unroll
    for (int i = 0; i < 8; i++) {
#pragma unroll
      for (int j = 0; j < 4; j++) y += S[i * 4 + j] * cv[i][j];
    }
    ybuf[((b * KD + k) * LT + p) * DI + tid] += y * cumv;
  }
}

// ---------------- Kernel 7: merge + LN + gelu + *silu(z) + out_proj ----------------
__global__ __launch_bounds__(192) void k_out(const float* __restrict__ ybuf,
                                             const float* __restrict__ zs,
                                             const float* __restrict__ ln_g,
                                             const float* __restrict__ ln_b,
                                             const float* __restrict__ Wo,
                                             float* __restrict__ out) {
  const int PP = 4;
  int pos0 = blockIdx.x * PP;
  int b = pos0 / LT, p0 = pos0 % LT;
  int tid = threadIdx.x;  // 0..191 = channel
  float v[PP], s1[PP], s2[PP];
#pragma unroll
  for (int q = 0; q < PP; q++) {
    float acc = 0.f;
#pragma unroll
    for (int k = 0; k < KD; k++) acc += ybuf[((b * KD + k) * LT + p0 + q) * DI + tid];
    v[q] = acc; s1[q] = acc; s2[q] = acc * acc;
  }
#pragma unroll
  for (int off = 32; off; off >>= 1) {
#pragma unroll
    for (int q = 0; q < PP; q++) {
      s1[q] += __shfl_down(s1[q], off, 64);
      s2[q] += __shfl_down(s2[q], off, 64);
    }
  }
  __shared__ float rs1[3][PP], rs2[3][PP];
  int wave = tid >> 6, lane = tid & 63;
  if (lane == 0) {
#pragma unroll
    for (int q = 0; q < PP; q++) { rs1[wave][q] = s1[q]; rs2[wave][q] = s2[q]; }
  }
  __syncthreads();
  __shared__ float su[PP][DI];
  float g = ln_g[tid], be = ln_b[tid];
#pragma unroll
  for (int q = 0; q < PP; q++) {
    float mean = (rs1[0][q] + rs1[1][q] + rs1[2][q]) * (1.f / 192.f);
    float var = (rs2[0][q] + rs2[1][q] + rs2[2][q]) * (1.f / 192.f) - mean * mean;
    float rstd = rsqrtf(var + 1e-5f);
    float t = (v[q] - mean) * rstd * g + be;
    float ge = 0.5f * t * (1.f + erff(t * 0.70710678118f));
    su[q][tid] = ge * zs[(pos0 + q) * DI + tid];
  }
  __syncthreads();
  int o = tid % DM, half = tid / DM;
  const float* wr = Wo + o * DI + half * DM;
  float acc[PP];
#pragma unroll
  for (int q = 0; q < PP; q++) acc[q] = 0.f;
  for (int j = 0; j < DM; j++) {
    float w = wr[j];
#pragma unroll
    for (int q = 0; q < PP; q++) acc[q] += w * su[q][half * DM + j];
  }
  __shared__ float part[PP][DI];
#pragma unroll
  for (int q = 0; q < PP; q++) part[q][tid] = acc[q];
  __syncthreads();
  if (tid < DM) {
#pragma unroll
    for (int q = 0; q < PP; q++)
      out[(pos0 + q) * DM + tid] = part[q][tid] + part[q][tid + DM];
  }
}

extern "C" void kernel_launch(void* const* d_in, const int* in_sizes, int n_in,
                              void* d_out, int out_size, void* d_ws, size_t ws_size,
                              hipStream_t stream) {
  const float* x       = (const float*)d_in[0];
  const float* Wi      = (const float*)d_in[1];
  const float* cw      = (const float*)d_in[2];
  const float* cb      = (const float*)d_in[3];
  const float* Wp      = (const float*)d_in[4];
  const float* Ds      = (const float*)d_in[5];
  const float* A_logs  = (const float*)d_in[6];
  const float* dt_bias = (const float*)d_in[7];
  const float* ln_g    = (const float*)d_in[8];
  const float* ln_b    = (const float*)d_in[9];
  const float* Wo      = (const float*)d_in[10];
  float* out = (float*)d_out;

  float* ws = (float*)d_ws;
  float* xi    = ws;                       // NPOS*DI
  float* zs    = xi + (size_t)NPOS * DI;
  float* xc    = zs + (size_t)NPOS * DI;
  float* dtb   = xc + (size_t)NPOS * DI;   // NPOS*KD*RK
  float* dAb   = dtb + (size_t)NPOS * KD * RK;
  float* Bsb   = dAb + (size_t)NPOS * KD * RK;   // NPOS*KD*NS
  float* Csb   = Bsb + (size_t)NPOS * KD * NS;
  float* cum   = Csb + (size_t)NPOS * KD * NS;   // NPOS*KD*RK
  float* ybuf  = cum + (size_t)NPOS * KD * RK;   // NB*KD*LT*DI
  float* Send  = ybuf + (size_t)NB * KD * LT * DI;  // SEQ*NC*ELEM (in-place prefix)
  float* Pend  = Send + (size_t)SEQ * NC * ELEM;    // SEQ*NC*RK
  float* WpbF  = Pend + (size_t)SEQ * NC * RK;      // NOP*DI bf16 = NOP*DI/2 floats
  // xcb (bf16 conv copy) aliases Send: dead until scanA overwrites it.
  unsigned short* xcb = (unsigned short*)Send;
  unsigned short* Wpb = (unsigned short*)WpbF;

  k_inproj<<<NPOS / 16, 384, 0, stream>>>(x, Wi, xi, zs);
  k_conv<<<(NPOS * DI + 255) / 256, 256, 0, stream>>>(xi, cw, cb, xc, xcb);
  k_wprep<<<(NOP * DI + 255) / 256, 256, 0, stream>>>(Wp, Wpb);
  k_xproj<<<NPOS / 32, 128, 0, stream>>>(xcb, Wpb, A_logs, dt_bias, dtb, dAb, Bsb, Csb);
  k_scanA<<<NB * KD * NC, 192, 0, stream>>>(xc, dtb, dAb, Bsb, Csb, Ds, ybuf, cum, Send, Pend);
  k_scanB<<<SEQ * (ELEM / 256), 256, 0, stream>>>(Send, Pend);
  k_scanC<<<NB * KD * NC, 192, 0, stream>>>(Csb, cum, Send, ybuf);
  k_out<<<NPOS / 4, 192, 0, stream>>>(ybuf, zs, ln_g, ln_b, Wo, out);
}